// Round 3
// baseline (118.386 us; speedup 1.0000x reference)
//
#include <hip/hip_runtime.h>
#include <math.h>

namespace {

constexpr int KK = 4;
constexpr int DD = 16;
constexpr int BLOCK = 256;
constexpr int PTS = 2;                       // points per thread
constexpr int PBLK = BLOCK * PTS;            // 512 points per block (32 KB)
constexpr float LOG2PI = 1.8378770664093453f;
constexpr float INV_SQRT2 = 0.70710678118654752f;   // folds the 0.5 into Linv

// Workspace layout (floats):
//   [0    .. 1023]  Linv_scaled[k][i][j]   ((1/sqrt2) * inv(L_k), upper-tri)
//   [1024 .. 1087]  W[k][i] = Linv_scaled_k . mu_k
//   [1088 .. 1091]  C0[k]   = log(phi_k) - 8*log(2pi) - logdet_k
constexpr int WOFF_W  = KK * DD * DD;        // 1024
constexpr int WOFF_C0 = WOFF_W + KK * DD;    // 1088

// ---------------------------------------------------------------------------
// Prep kernel: 1 block, 64 threads. Thread (k,j) computes column j of
// inv(L_k) by back substitution (precise divide -- off the hot path).
// ---------------------------------------------------------------------------
__global__ void gmm_prep(const float* __restrict__ phi, const float* __restrict__ mu,
                         const float* __restrict__ L, float* __restrict__ ws)
{
    const int tid = threadIdx.x;             // 0..63
    const int k = tid >> 4;
    const int j = tid & 15;
    const float* __restrict__ Lk = L + k * DD * DD;

    float xv[DD];
    #pragma unroll
    for (int m = 0; m < DD; ++m) xv[m] = 0.0f;
    #pragma unroll
    for (int i = DD - 1; i >= 0; --i) {
        float s = (i == j) ? 1.0f : 0.0f;
        #pragma unroll
        for (int m = i + 1; m < DD; ++m)
            s = fmaf(-Lk[i * DD + m], xv[m], s);      // xv[m]==0 for m>j
        xv[i] = (i <= j) ? (s / Lk[i * DD + i]) : 0.0f;
    }
    #pragma unroll
    for (int i = 0; i < DD; ++i)
        ws[k * DD * DD + i * DD + j] = xv[i] * INV_SQRT2;

    __syncthreads();   // one block: global writes above visible after barrier

    // Row j of W_k (thread's j reused as row index).
    float w = 0.0f;
    #pragma unroll
    for (int jj = 0; jj < DD; ++jj)
        w = fmaf(ws[k * DD * DD + j * DD + jj], mu[k * DD + jj], w);
    ws[WOFF_W + k * DD + j] = w;

    if (tid < KK) {
        float logdet = 0.0f;
        #pragma unroll
        for (int i = 0; i < DD; ++i)
            logdet += __logf(L[tid * DD * DD + i * DD + i]);
        ws[WOFF_C0 + tid] = __logf(phi[tid]) - 8.0f * LOG2PI - logdet;
    }
}

// ---------------------------------------------------------------------------
// Main kernel. z is staged through LDS so the global reads are FULLY
// coalesced (lane i <- base + i*16B, 1 KB per wave instruction) instead of
// 16B-per-lane at 128B stride (64 distinct lines per instruction).
//
// LDS layout: XOR-swizzle the 16B-slot index with the 128B-revolution index:
//   phys = (lin & ~7) | ((lin ^ (lin >> 3)) & 7)
// Write side: bijective within each 128B revolution -> minimal 8-cycle b128.
// Read side (thread t reads row 2t+p, chunk c): slot = ((p<<2)|c) ^ (t&7)
// covers all 8 bank-quads across the wave -> minimal 8-cycle b128.
// (Unswizzled, the row reads would be a 64-way bank conflict.)
// ---------------------------------------------------------------------------
__global__ __launch_bounds__(BLOCK, 4)
void gmm_energy(const float* __restrict__ z, const float* __restrict__ cw,
                float* __restrict__ out, int N, int full_blocks)
{
    __shared__ float4 sz[PBLK * 4];          // 32 KB
    const int tid = threadIdx.x;
    const int base = blockIdx.x * PBLK + tid * PTS;

    float zr[DD][PTS];                       // [dim][point] -> packed-FMA pairs

    if (blockIdx.x < full_blocks) {
        // ---- coalesced stage: 8 x (1 KB/wave) ----
        const float4* __restrict__ zsrc =
            reinterpret_cast<const float4*>(z) + (size_t)blockIdx.x * (PBLK * 4);
        #pragma unroll
        for (int s = 0; s < 8; ++s) {
            const int lin = s * BLOCK + tid;                       // 0..2047
            const int swz = (lin & ~7) | ((lin ^ (lin >> 3)) & 7);
            sz[swz] = zsrc[lin];
        }
        __syncthreads();
        // ---- swizzled row read-back ----
        #pragma unroll
        for (int p = 0; p < PTS; ++p) {
            const int r = tid * PTS + p;
            const int rev = r >> 1;                                // == tid
            #pragma unroll
            for (int c = 0; c < 4; ++c) {
                const int slot = (((r & 1) << 2) | c) ^ (rev & 7);
                const float4 v = sz[rev * 8 + slot];
                zr[c * 4 + 0][p] = v.x;
                zr[c * 4 + 1][p] = v.y;
                zr[c * 4 + 2][p] = v.z;
                zr[c * 4 + 3][p] = v.w;
            }
        }
    } else {
        // ---- tail block (<= 1 per grid): predicated scalar path ----
        #pragma unroll
        for (int p = 0; p < PTS; ++p) {
            if (base + p < N) {
                const float4* zp = reinterpret_cast<const float4*>(z + (size_t)(base + p) * DD);
                #pragma unroll
                for (int c = 0; c < 4; ++c) {
                    const float4 v = zp[c];
                    zr[c * 4 + 0][p] = v.x;
                    zr[c * 4 + 1][p] = v.y;
                    zr[c * 4 + 2][p] = v.z;
                    zr[c * 4 + 3][p] = v.w;
                }
            } else {
                #pragma unroll
                for (int d = 0; d < DD; ++d) zr[d][p] = 0.0f;
            }
        }
    }

    // ---- per-component Mahalanobis via scaled triangular matvec ----
    // acc = (1/sqrt2)*(Linv_row_i . z) - w_i ; q = sum acc^2 = 0.5*Mahalanobis
    float lg[KK][PTS];
    #pragma unroll
    for (int k = 0; k < KK; ++k) {
        const float* __restrict__ Ck = cw + k * DD * DD;     // uniform -> SGPR
        const float* __restrict__ Wk = cw + WOFF_W + k * DD;
        float q0 = 0.0f, q1 = 0.0f;
        #pragma unroll
        for (int i = 0; i < DD; ++i) {
            const float wk = Wk[i];
            const float cd = Ck[i * DD + i];
            float a0 = fmaf(cd, zr[i][0], -wk);
            float a1 = fmaf(cd, zr[i][1], -wk);
            #pragma unroll
            for (int j = i + 1; j < DD; ++j) {
                const float cf = Ck[i * DD + j];
                a0 = fmaf(cf, zr[j][0], a0);
                a1 = fmaf(cf, zr[j][1], a1);
            }
            q0 = fmaf(a0, a0, q0);
            q1 = fmaf(a1, a1, q1);
        }
        const float c0 = cw[WOFF_C0 + k];
        lg[k][0] = c0 - q0;                                  // 0.5 already folded
        lg[k][1] = c0 - q1;
    }

    // ---- logsumexp over K=4, negate, store ----
    float e[PTS];
    #pragma unroll
    for (int p = 0; p < PTS; ++p) {
        float m01 = fmaxf(lg[0][p], lg[1][p]);
        float m23 = fmaxf(lg[2][p], lg[3][p]);
        float m = fmaxf(m01, m23);
        float s = __expf(lg[0][p] - m) + __expf(lg[1][p] - m)
                + __expf(lg[2][p] - m) + __expf(lg[3][p] - m);
        e[p] = -(m + __logf(s));
    }

    if (base + PTS <= N) {
        float2 res;
        res.x = e[0]; res.y = e[1];
        *reinterpret_cast<float2*>(out + base) = res;
    } else {
        #pragma unroll
        for (int p = 0; p < PTS; ++p) {
            if (base + p < N) out[base + p] = e[p];
        }
    }
}

} // namespace

extern "C" void kernel_launch(void* const* d_in, const int* in_sizes, int n_in,
                              void* d_out, int out_size, void* d_ws, size_t ws_size,
                              hipStream_t stream) {
    const float* z   = (const float*)d_in[0];   // [N,16]
    const float* phi = (const float*)d_in[1];   // [4]
    const float* mu  = (const float*)d_in[2];   // [4,16]
    const float* L   = (const float*)d_in[3];   // [4,16,16] upper-triangular
    float* out = (float*)d_out;                 // [N]
    float* ws  = (float*)d_ws;                  // >= 4368 B needed
    const int N = in_sizes[0] / DD;

    gmm_prep<<<1, 64, 0, stream>>>(phi, mu, L, ws);

    const int full_blocks = N / PBLK;
    const int grid = (N + PBLK - 1) / PBLK;
    gmm_energy<<<grid, BLOCK, 0, stream>>>(z, ws, out, N, full_blocks);
}